// Round 6
// baseline (450.998 us; speedup 1.0000x reference)
//
#include <hip/hip_runtime.h>
#include <stdint.h>
#include <math.h>

#define NAG 8192
#define NC  128          // Cp16 row stride: exactly the 128 msg features
#define NSPLIT 16        // K splits of 512 (fp16 private partials, no atomics)
#define LDB2 136         // B LDS row stride in shorts (128 + 8 pad)

typedef __attribute__((ext_vector_type(8))) short short8;
typedef __attribute__((ext_vector_type(4))) float floatx4;

__device__ __forceinline__ float bf2f(unsigned short u) {
    union { uint32_t i; float f; } v; v.i = ((uint32_t)u) << 16; return v.f;
}
__device__ __forceinline__ unsigned short f2bf(float f) {
    union { float f; uint32_t i; } v; v.f = f;
    uint32_t x = v.i;
    return (unsigned short)((x + 0x7FFFu + ((x >> 16) & 1u)) >> 16);  // RNE
}
__device__ __forceinline__ unsigned short f2h(float f) {
    union { _Float16 h; unsigned short u; } v; v.h = (_Float16)f; return v.u;
}
__device__ __forceinline__ float h2f(unsigned short u) {
    union { _Float16 h; unsigned short u; } v; v.u = u; return (float)v.h;
}
// per-wave dtype self-detection (uniform ballot in every wave; no cross-block flag)
__device__ __forceinline__ bool detect_f32(const void* W1, int t) {
    const unsigned short* w = (const unsigned short*)W1;
    int l = t & 63, big = 0;
    #pragma unroll
    for (int j = 0; j < 8; ++j) {
        float v = bf2f(w[l * 8 + j]);
        if (!(fabsf(v) <= 1e6f)) big = 1;   // catches huge and NaN (fp32 mantissa noise)
    }
    return __ballot(big) != 0ull;
}

// ---------------- Kernel A: fused bitpack (blocks 0..2047) + encoder (2048..2303) ----------------
__global__ __launch_bounds__(256) void kA_pack_encode(
    const int* __restrict__ adj,              // [8192][8192] int32 {0,1}
    unsigned long long* __restrict__ bits,    // [8192*8192/64] packed, row-major
    const void* __restrict__ obs,             // [8192][64]
    const void* __restrict__ W1,              // [64][128]
    const void* __restrict__ b1,              // [128]
    float* __restrict__ h_f32,                // [8192][128]
    unsigned short* __restrict__ hT)          // [128][8192] bf16 (features only)
{
    const int t = threadIdx.x;
    if (blockIdx.x < 2048) {
        // ---- bitpack: pure streaming, 1KB contiguous per ballot, 4KB per wave-iter ----
        const int lane = t & 63;
        const int gw = blockIdx.x * 4 + (t >> 6);         // global wave id 0..8191
        for (int it = 0; it < 32; ++it) {
            size_t u = ((size_t)it * 8192 + gw) * 4;      // 4 u64-units per wave per iter
            size_t col = u * 64 + lane;
            unsigned long long m0 = __ballot(adj[col]       != 0);
            unsigned long long m1 = __ballot(adj[col + 64]  != 0);
            unsigned long long m2 = __ballot(adj[col + 128] != 0);
            unsigned long long m3 = __ballot(adj[col + 192] != 0);
            if (lane == 0) {
                bits[u]     = m0;
                bits[u + 1] = m1;
                bits[u + 2] = m2;
                bits[u + 3] = m3;
            }
        }
        return;
    }
    // ---- encoder: h = tanh(obs@W1+b1) ----
    __shared__ float obs_lds[32][68];
    __shared__ unsigned short ht_lds[128][33];
    const int abase = (blockIdx.x - 2048) * 32;
    const bool isf = detect_f32(W1, t);

    {   // stage obs tile 32x64
        int a = t >> 3, c0 = (t & 7) * 8;
        if (isf) {
            const float* p = (const float*)obs;
            #pragma unroll
            for (int j = 0; j < 8; ++j)
                obs_lds[a][c0 + j] = p[(size_t)(abase + a) * 64 + c0 + j];
        } else {
            const unsigned short* p = (const unsigned short*)obs;
            #pragma unroll
            for (int j = 0; j < 8; ++j)
                obs_lds[a][c0 + j] = bf2f(p[(size_t)(abase + a) * 64 + c0 + j]);
        }
    }
    __syncthreads();

    const int o = t & 127;
    const int half = t >> 7;          // wave-uniform
    float acc[16];
    if (isf) {
        const float* Wp = (const float*)W1;
        float bias = ((const float*)b1)[o];
        #pragma unroll
        for (int i = 0; i < 16; ++i) acc[i] = bias;
        for (int k0 = 0; k0 < 64; k0 += 8) {
            float w[8];
            #pragma unroll
            for (int j = 0; j < 8; ++j) w[j] = Wp[(k0 + j) * 128 + o];
            #pragma unroll
            for (int j = 0; j < 8; ++j)
                #pragma unroll
                for (int i = 0; i < 16; ++i)
                    acc[i] = fmaf(obs_lds[half * 16 + i][k0 + j], w[j], acc[i]);
        }
    } else {
        const unsigned short* Wp = (const unsigned short*)W1;
        float bias = bf2f(((const unsigned short*)b1)[o]);
        #pragma unroll
        for (int i = 0; i < 16; ++i) acc[i] = bias;
        for (int k0 = 0; k0 < 64; k0 += 8) {
            float w[8];
            #pragma unroll
            for (int j = 0; j < 8; ++j) w[j] = bf2f(Wp[(k0 + j) * 128 + o]);
            #pragma unroll
            for (int j = 0; j < 8; ++j)
                #pragma unroll
                for (int i = 0; i < 16; ++i)
                    acc[i] = fmaf(obs_lds[half * 16 + i][k0 + j], w[j], acc[i]);
        }
    }
    #pragma unroll
    for (int i = 0; i < 16; ++i) {
        float th = tanhf(acc[i]);
        int a = half * 16 + i;
        h_f32[(size_t)(abase + a) * 128 + o] = th;
        ht_lds[o][a] = f2bf(th);
    }
    __syncthreads();

    for (int p = 0; p < 16; ++p) {    // 128 feature rows only (no constant rows)
        int n = p * 8 + (t >> 5);
        int a = t & 31;
        hT[(size_t)n * NAG + abase + a] = ht_lds[n][a];
    }
}

// ---------------- Kernel 2: Cp16[ks] = bits-adj @ h  (bf16 MFMA) ----------------
// R5 lesson: BM=128 (2 row-groups/wave) halves LDS-read + staging bytes, but at
// grid 512 it cost occupancy (2 blocks/CU). Fix: NSPLIT=16 (K=512/block) restores
// grid 1024 -> 4 blocks/CU, 16 waves/CU, while keeping both byte halvings.
// LDS 34.8 KB x4 = 139 KB/CU; VGPR ~110 under __launch_bounds__(256,4).
__global__ __launch_bounds__(256, 4) void k2_msggemm(
    const uint32_t* __restrict__ bits,        // [8192][256] u32, bit b of word w = col w*32+b
    const unsigned short* __restrict__ hT,    // [128][8192] bf16
    unsigned short* __restrict__ Cp16)        // [NSPLIT][8192][128] fp16
{
    __shared__ __align__(16) unsigned short Blds[128 * LDB2];  // 34,816 B
    const int t = threadIdx.x;
    const int mtile = blockIdx.x & 63;        // 64 M-tiles of 128 rows
    const int ks = blockIdx.x >> 6;           // 16 K-splits of 512
    const int row0 = mtile * 128;
    const int kbeg = ks * 512;

    const int wave = t >> 6, lane = t & 63;
    const int fm = lane & 15, quad = lane >> 4;

    floatx4 acc0[8], acc1[8];
    #pragma unroll
    for (int i = 0; i < 8; ++i) { acc0[i] = (floatx4)0.f; acc1[i] = (floatx4)0.f; }

    const int arow0 = row0 + wave * 32 + fm;       // row-group 0
    const uint32_t* aWp0 = bits + (size_t)arow0 * 256 + (kbeg >> 5);
    const uint32_t* aWp1 = aWp0 + 16 * 256;        // row-group 1 (+16 rows)

    for (int ss = 0; ss < 4; ++ss) {          // 4 sub-slices of 128 k
        if (ss) __syncthreads();              // prior compute done before LDS overwrite
        // stage B[128][128] (L2/L3-hot hT): 2048 16B-chunks over 256 threads = 8 each
        #pragma unroll
        for (int i = 0; i < 8; ++i) {
            int idx = i * 256 + t;
            int row = idx >> 4, ch = idx & 15;
            uint4 v = *reinterpret_cast<const uint4*>(hT + (size_t)row * NAG + kbeg + ss * 128 + ch * 8);
            *reinterpret_cast<uint4*>(&Blds[row * LDB2 + ch * 8]) = v;
        }
        // lane A-bits for this sub-slice: 2 row-groups x 4 u32 = 32 B
        int4 a0 = *reinterpret_cast<const int4*>(aWp0 + ss * 4);
        int4 a1 = *reinterpret_cast<const int4*>(aWp1 + ss * 4);
        uint32_t aw0[4] = {(uint32_t)a0.x, (uint32_t)a0.y, (uint32_t)a0.z, (uint32_t)a0.w};
        uint32_t aw1[4] = {(uint32_t)a1.x, (uint32_t)a1.y, (uint32_t)a1.z, (uint32_t)a1.w};
        __syncthreads();                      // B + bits resident
        #pragma unroll
        for (int kw = 0; kw < 4; ++kw) {      // 4 windows of 32 k
            uint32_t b0 = (aw0[kw] >> (quad * 8)) & 0xFFu;
            uint32_t b1 = (aw1[kw] >> (quad * 8)) & 0xFFu;
            union { uint32_t u[4]; short8 s; } af0, af1;
            #pragma unroll
            for (int p = 0; p < 4; ++p) {
                uint32_t bb0 = b0 >> (2 * p);
                uint32_t bb1 = b1 >> (2 * p);
                af0.u[p] = ((bb0 & 1u) | ((bb0 & 2u) << 15)) * 0x3F80u;   // {0,1}->bf16 pair, exact
                af1.u[p] = ((bb1 & 1u) | ((bb1 & 2u) << 15)) * 0x3F80u;
            }
            #pragma unroll
            for (int j = 0; j < 8; ++j) {
                short8 bf = *reinterpret_cast<const short8*>(&Blds[(j * 16 + fm) * LDB2 + kw * 32 + quad * 8]);
                acc0[j] = __builtin_amdgcn_mfma_f32_16x16x32_bf16(af0.s, bf, acc0[j], 0, 0, 0);
                acc1[j] = __builtin_amdgcn_mfma_f32_16x16x32_bf16(af1.s, bf, acc1[j], 0, 0, 0);
            }
        }
    }

    // epilogue: C/D layout col=lane&15, row=quad*4+reg; fp16 private partial per K-split
    unsigned short* out = Cp16 + (size_t)ks * (NAG * NC);
    #pragma unroll
    for (int j = 0; j < 8; ++j) {
        int col = j * 16 + fm;
        #pragma unroll
        for (int r = 0; r < 4; ++r) {
            int row = row0 + wave * 32 + quad * 4 + r;
            out[(size_t)row * NC + col]        = f2h(acc0[j][r]);
            out[(size_t)(row + 16) * NC + col] = f2h(acc1[j][r]);
        }
    }
}

// ---------------- Kernel 3: deg = popcount(bits row); reduce partials; actor MLP ----------------
__global__ __launch_bounds__(256) void k3_actor(
    const float* __restrict__ h_f32,            // [8192][128]
    const unsigned short* __restrict__ Cp16,    // [NSPLIT][8192][128] fp16
    const unsigned long long* __restrict__ bits,// [8192][128] u64
    const void* __restrict__ W1,                // for dtype self-detection
    const void* __restrict__ W2,                // [256][128]
    const void* __restrict__ b2,                // [128]
    const void* __restrict__ W3,                // [128][16]
    const void* __restrict__ b3,                // [16]
    void* __restrict__ out)                     // [8192][16]
{
    __shared__ float4 comb4[8][66];   // [agent][c-quad], c = 0..255
    __shared__ float hid[8][132];
    __shared__ int degp[8][33];
    __shared__ float inv_lds[8];
    const int t = threadIdx.x;
    const int abase = blockIdx.x * 8;
    const bool isf = detect_f32(W1, t);
    const size_t PS = (size_t)NAG * NC;

    {   // deg: 32 threads per agent, 4 u64 popcounts each (exact integer degree)
        int a = t >> 5, j = t & 31;
        const unsigned long long* bp = bits + (size_t)(abase + a) * 128 + j * 4;
        degp[a][j] = __popcll(bp[0]) + __popcll(bp[1]) + __popcll(bp[2]) + __popcll(bp[3]);
    }
    __syncthreads();
    if (t < 8) {
        int d = 0;
        #pragma unroll
        for (int j = 0; j < 32; ++j) d += degp[t][j];
        inv_lds[t] = 1.0f / fmaxf((float)d, 1.0f);
    }
    __syncthreads();

    // stage comb: 8 agents x 64 c-quads = 512 tasks over 256 threads
    #pragma unroll
    for (int jj = 0; jj < 2; ++jj) {
        int idx = jj * 256 + t;
        int a = idx >> 6, q = idx & 63;
        float4 v;
        if (q < 32) {   // h part
            v = *reinterpret_cast<const float4*>(h_f32 + (size_t)(abase + a) * 128 + q * 4);
        } else {        // msg part: sum NSPLIT fp16 partials, scale by 1/deg
            int f = (q - 32) * 4;
            float s0 = 0.f, s1 = 0.f, s2 = 0.f, s3 = 0.f;
            #pragma unroll
            for (int s = 0; s < NSPLIT; ++s) {
                ushort4 p = *reinterpret_cast<const ushort4*>(Cp16 + s * PS + (size_t)(abase + a) * NC + f);
                s0 += h2f(p.x); s1 += h2f(p.y); s2 += h2f(p.z); s3 += h2f(p.w);
            }
            float sc = inv_lds[a];
            v = make_float4(s0 * sc, s1 * sc, s2 * sc, s3 * sc);
        }
        comb4[a][q] = v;
    }
    __syncthreads();

    const int o = t & 127, half = t >> 7;   // 4 agents per half
    float acc[4];
    if (isf) {
        const float* Wp = (const float*)W2;
        float bias = ((const float*)b2)[o];
        #pragma unroll
        for (int i = 0; i < 4; ++i) acc[i] = bias;
        for (int cq = 0; cq < 64; ++cq) {
            float w0 = Wp[(cq * 4 + 0) * 128 + o];
            float w1 = Wp[(cq * 4 + 1) * 128 + o];
            float w2 = Wp[(cq * 4 + 2) * 128 + o];
            float w3 = Wp[(cq * 4 + 3) * 128 + o];
            #pragma unroll
            for (int i = 0; i < 4; ++i) {
                float4 v = comb4[half * 4 + i][cq];
                acc[i] = fmaf(v.x, w0, acc[i]);
                acc[i] = fmaf(v.y, w1, acc[i]);
                acc[i] = fmaf(v.z, w2, acc[i]);
                acc[i] = fmaf(v.w, w3, acc[i]);
            }
        }
    } else {
        const unsigned short* Wp = (const unsigned short*)W2;
        float bias = bf2f(((const unsigned short*)b2)[o]);
        #pragma unroll
        for (int i = 0; i < 4; ++i) acc[i] = bias;
        for (int cq = 0; cq < 64; ++cq) {
            float w0 = bf2f(Wp[(cq * 4 + 0) * 128 + o]);
            float w1 = bf2f(Wp[(cq * 4 + 1) * 128 + o]);
            float w2 = bf2f(Wp[(cq * 4 + 2) * 128 + o]);
            float w3 = bf2f(Wp[(cq * 4 + 3) * 128 + o]);
            #pragma unroll
            for (int i = 0; i < 4; ++i) {
                float4 v = comb4[half * 4 + i][cq];
                acc[i] = fmaf(v.x, w0, acc[i]);
                acc[i] = fmaf(v.y, w1, acc[i]);
                acc[i] = fmaf(v.z, w2, acc[i]);
                acc[i] = fmaf(v.w, w3, acc[i]);
            }
        }
    }
    #pragma unroll
    for (int i = 0; i < 4; ++i)
        hid[half * 4 + i][o] = tanhf(acc[i]);
    __syncthreads();

    if (t < 128) {   // 8 agents x 16 outputs
        const int q = t & 15, ar = t >> 4;
        float l;
        if (isf) {
            const float* Wp = (const float*)W3;
            l = ((const float*)b3)[q];
            #pragma unroll 4
            for (int oo = 0; oo < 128; ++oo)
                l = fmaf(hid[ar][oo], Wp[oo * 16 + q], l);
        } else {
            const unsigned short* Wp = (const unsigned short*)W3;
            l = bf2f(((const unsigned short*)b3)[q]);
            #pragma unroll 4
            for (int oo = 0; oo < 128; ++oo)
                l = fmaf(hid[ar][oo], bf2f(Wp[oo * 16 + q]), l);
        }
        size_t i0 = (size_t)(abase + ar) * 16 + q;
        if (isf) ((float*)out)[i0] = l;
        else     ((unsigned short*)out)[i0] = f2bf(l);
    }
}

extern "C" void kernel_launch(void* const* d_in, const int* in_sizes, int n_in,
                              void* d_out, int out_size, void* d_ws, size_t ws_size,
                              hipStream_t stream) {
    const void* obs = d_in[0];
    const int*  adj = (const int*)d_in[1];
    const void* W1  = d_in[2];
    const void* b1  = d_in[3];
    const void* W2  = d_in[4];
    const void* b2  = d_in[5];
    const void* W3  = d_in[6];
    const void* b3  = d_in[7];

    char* ws = (char*)d_ws;
    unsigned short* hT   = (unsigned short*)(ws);                    // 128*8192*2    =  2,097,152 B
    float*          h_f32= (float*)(ws + 2097152);                   // 8192*128*4    =  4,194,304 B
    unsigned short* Cp16 = (unsigned short*)(ws + 6291456);          // 16*8192*128*2 = 33,554,432 B
    unsigned long long* bits = (unsigned long long*)(ws + 39845888); // 8192*8192/8   =  8,388,608 B
                                                                     // total ~48.2 MB

    hipLaunchKernelGGL(kA_pack_encode, dim3(2304), dim3(256), 0, stream,
                       adj, bits, obs, W1, b1, h_f32, hT);
    hipLaunchKernelGGL(k2_msggemm, dim3(1024), dim3(256), 0, stream,
                       (const uint32_t*)bits, hT, Cp16);
    hipLaunchKernelGGL(k3_actor, dim3(1024), dim3(256), 0, stream,
                       h_f32, Cp16, bits, W1, W2, b2, W3, b3, d_out);
}

// Round 7
// 449.806 us; speedup vs baseline: 1.0026x; 1.0026x over previous
//
#include <hip/hip_runtime.h>
#include <stdint.h>
#include <math.h>

#define NAG 8192
#define NC  128          // Cp16 row stride: exactly the 128 msg features
#define NSPLIT 8         // K splits of 1024 (fp16 private partials, no atomics)
#define LDB2 136         // B LDS row stride in shorts (128 + 8 pad)

typedef __attribute__((ext_vector_type(8))) short short8;
typedef __attribute__((ext_vector_type(4))) float floatx4;

__device__ __forceinline__ float bf2f(unsigned short u) {
    union { uint32_t i; float f; } v; v.i = ((uint32_t)u) << 16; return v.f;
}
__device__ __forceinline__ unsigned short f2bf(float f) {
    union { float f; uint32_t i; } v; v.f = f;
    uint32_t x = v.i;
    return (unsigned short)((x + 0x7FFFu + ((x >> 16) & 1u)) >> 16);  // RNE
}
__device__ __forceinline__ unsigned short f2h(float f) {
    union { _Float16 h; unsigned short u; } v; v.h = (_Float16)f; return v.u;
}
__device__ __forceinline__ float h2f(unsigned short u) {
    union { _Float16 h; unsigned short u; } v; v.u = u; return (float)v.h;
}
// per-wave dtype self-detection (uniform ballot in every wave; no cross-block flag)
__device__ __forceinline__ bool detect_f32(const void* W1, int t) {
    const unsigned short* w = (const unsigned short*)W1;
    int l = t & 63, big = 0;
    #pragma unroll
    for (int j = 0; j < 8; ++j) {
        float v = bf2f(w[l * 8 + j]);
        if (!(fabsf(v) <= 1e6f)) big = 1;   // catches huge and NaN (fp32 mantissa noise)
    }
    return __ballot(big) != 0ull;
}

// ---------------- Kernel A: fused bitpack (blocks 0..2047) + encoder (2048..2303) ----------------
__global__ __launch_bounds__(256) void kA_pack_encode(
    const int* __restrict__ adj,              // [8192][8192] int32 {0,1}
    unsigned long long* __restrict__ bits,    // [8192*8192/64] packed, row-major
    const void* __restrict__ obs,             // [8192][64]
    const void* __restrict__ W1,              // [64][128]
    const void* __restrict__ b1,              // [128]
    float* __restrict__ h_f32,                // [8192][128]
    unsigned short* __restrict__ hT)          // [128][8192] bf16 (features only)
{
    const int t = threadIdx.x;
    if (blockIdx.x < 2048) {
        // ---- bitpack: pure streaming, 1KB contiguous per ballot, 4KB per wave-iter ----
        const int lane = t & 63;
        const int gw = blockIdx.x * 4 + (t >> 6);         // global wave id 0..8191
        for (int it = 0; it < 32; ++it) {
            size_t u = ((size_t)it * 8192 + gw) * 4;      // 4 u64-units per wave per iter
            size_t col = u * 64 + lane;
            unsigned long long m0 = __ballot(adj[col]       != 0);
            unsigned long long m1 = __ballot(adj[col + 64]  != 0);
            unsigned long long m2 = __ballot(adj[col + 128] != 0);
            unsigned long long m3 = __ballot(adj[col + 192] != 0);
            if (lane == 0) {
                bits[u]     = m0;
                bits[u + 1] = m1;
                bits[u + 2] = m2;
                bits[u + 3] = m3;
            }
        }
        return;
    }
    // ---- encoder: h = tanh(obs@W1+b1) ----
    __shared__ float obs_lds[32][68];
    __shared__ unsigned short ht_lds[128][33];
    const int abase = (blockIdx.x - 2048) * 32;
    const bool isf = detect_f32(W1, t);

    {   // stage obs tile 32x64
        int a = t >> 3, c0 = (t & 7) * 8;
        if (isf) {
            const float* p = (const float*)obs;
            #pragma unroll
            for (int j = 0; j < 8; ++j)
                obs_lds[a][c0 + j] = p[(size_t)(abase + a) * 64 + c0 + j];
        } else {
            const unsigned short* p = (const unsigned short*)obs;
            #pragma unroll
            for (int j = 0; j < 8; ++j)
                obs_lds[a][c0 + j] = bf2f(p[(size_t)(abase + a) * 64 + c0 + j]);
        }
    }
    __syncthreads();

    const int o = t & 127;
    const int half = t >> 7;          // wave-uniform
    float acc[16];
    if (isf) {
        const float* Wp = (const float*)W1;
        float bias = ((const float*)b1)[o];
        #pragma unroll
        for (int i = 0; i < 16; ++i) acc[i] = bias;
        for (int k0 = 0; k0 < 64; k0 += 8) {
            float w[8];
            #pragma unroll
            for (int j = 0; j < 8; ++j) w[j] = Wp[(k0 + j) * 128 + o];
            #pragma unroll
            for (int j = 0; j < 8; ++j)
                #pragma unroll
                for (int i = 0; i < 16; ++i)
                    acc[i] = fmaf(obs_lds[half * 16 + i][k0 + j], w[j], acc[i]);
        }
    } else {
        const unsigned short* Wp = (const unsigned short*)W1;
        float bias = bf2f(((const unsigned short*)b1)[o]);
        #pragma unroll
        for (int i = 0; i < 16; ++i) acc[i] = bias;
        for (int k0 = 0; k0 < 64; k0 += 8) {
            float w[8];
            #pragma unroll
            for (int j = 0; j < 8; ++j) w[j] = bf2f(Wp[(k0 + j) * 128 + o]);
            #pragma unroll
            for (int j = 0; j < 8; ++j)
                #pragma unroll
                for (int i = 0; i < 16; ++i)
                    acc[i] = fmaf(obs_lds[half * 16 + i][k0 + j], w[j], acc[i]);
        }
    }
    #pragma unroll
    for (int i = 0; i < 16; ++i) {
        float th = tanhf(acc[i]);
        int a = half * 16 + i;
        h_f32[(size_t)(abase + a) * 128 + o] = th;
        ht_lds[o][a] = f2bf(th);
    }
    __syncthreads();

    for (int p = 0; p < 16; ++p) {    // 128 feature rows only (no constant rows)
        int n = p * 8 + (t >> 5);
        int a = t & 31;
        hT[(size_t)n * NAG + abase + a] = ht_lds[n][a];
    }
}

// ---------------- Kernel 2: Cp16[ks] = bits-adj @ h  (bf16 MFMA, M x N split tiles) ----------------
// R5/R6 lesson: 2-row-groups/wave halves LDS-read+staging bytes, but K-split-based
// grid restoration pays in occupancy (R5) or partials traffic (R6). N-split pays in
// NEITHER: BM=128 x BN=64, grid = 64 mtiles x 2 nsplits x 8 ksplits = 1024 blocks
// (4/CU, 16 waves/CU = baseline), Cp16 unchanged. LDS reads 1.07GB->536MB, staging
// 268->134MB. Double-buffered LDS: 1 barrier/sub-slice (8 vs baseline 15), with
// T14 async-STAGE (issue loads before MFMA phase, ds_write after).
__global__ __launch_bounds__(256, 4) void k2_msggemm(
    const uint32_t* __restrict__ bits,        // [8192][256] u32, bit b of word w = col w*32+b
    const unsigned short* __restrict__ hT,    // [128][8192] bf16
    unsigned short* __restrict__ Cp16)        // [NSPLIT][8192][128] fp16
{
    __shared__ __align__(16) unsigned short Blds[2][64 * LDB2];  // 2 x 17,408 B = 34.8 KB
    const int t = threadIdx.x;
    const int mtile = blockIdx.x & 63;        // 64 M-tiles of 128 rows
    const int ns = (blockIdx.x >> 6) & 1;     // 2 N-splits of 64 features
    const int ks = blockIdx.x >> 7;           // 8 K-splits of 1024
    const int row0 = mtile * 128;
    const int n0 = ns * 64;
    const int kbeg = ks * 1024;

    const int wave = t >> 6, lane = t & 63;
    const int fm = lane & 15, quad = lane >> 4;

    floatx4 acc0[4], acc1[4];
    #pragma unroll
    for (int i = 0; i < 4; ++i) { acc0[i] = (floatx4)0.f; acc1[i] = (floatx4)0.f; }

    const int arow0 = row0 + wave * 32 + fm;       // row-group 0 (row-group 1 = +16)
    const uint32_t* aWp0 = bits + (size_t)arow0 * 256 + (kbeg >> 5);
    const uint32_t* aWp1 = aWp0 + 16 * 256;

    const unsigned short* hbase = hT + (size_t)n0 * NAG + kbeg;   // block's B panel

    // staging task decode (shared by prologue & loop): 64 rows x 16 chunks = 1024
    // 16B-chunks over 256 threads = 4 each
    {   // prologue: stage sub-slice 0 into buffer 0
        #pragma unroll
        for (int i = 0; i < 4; ++i) {
            int idx = i * 256 + t;
            int row = idx >> 4, ch = idx & 15;
            uint4 v = *reinterpret_cast<const uint4*>(hbase + (size_t)row * NAG + ch * 8);
            *reinterpret_cast<uint4*>(&Blds[0][row * LDB2 + ch * 8]) = v;
        }
        __syncthreads();
    }

    #pragma unroll 1
    for (int ss = 0; ss < 8; ++ss) {          // 8 sub-slices of 128 k
        const int cur = ss & 1;
        // T14 stage-split: issue next sub-slice's global loads EARLY (into regs)
        uint4 sv[4];
        if (ss < 7) {
            #pragma unroll
            for (int i = 0; i < 4; ++i) {
                int idx = i * 256 + t;
                int row = idx >> 4, ch = idx & 15;
                sv[i] = *reinterpret_cast<const uint4*>(hbase + (size_t)row * NAG + (ss + 1) * 128 + ch * 8);
            }
        }
        // lane A-bits for this sub-slice: 2 row-groups x 4 u32
        int4 a0 = *reinterpret_cast<const int4*>(aWp0 + ss * 4);
        int4 a1 = *reinterpret_cast<const int4*>(aWp1 + ss * 4);
        uint32_t aw0[4] = {(uint32_t)a0.x, (uint32_t)a0.y, (uint32_t)a0.z, (uint32_t)a0.w};
        uint32_t aw1[4] = {(uint32_t)a1.x, (uint32_t)a1.y, (uint32_t)a1.z, (uint32_t)a1.w};
        // MFMA phase on the current buffer (hides the in-flight stage loads)
        #pragma unroll
        for (int kw = 0; kw < 4; ++kw) {      // 4 windows of 32 k
            uint32_t b0 = (aw0[kw] >> (quad * 8)) & 0xFFu;
            uint32_t b1 = (aw1[kw] >> (quad * 8)) & 0xFFu;
            union { uint32_t u[4]; short8 s; } af0, af1;
            #pragma unroll
            for (int p = 0; p < 4; ++p) {
                uint32_t bb0 = b0 >> (2 * p);
                uint32_t bb1 = b1 >> (2 * p);
                af0.u[p] = ((bb0 & 1u) | ((bb0 & 2u) << 15)) * 0x3F80u;   // {0,1}->bf16 pair, exact
                af1.u[p] = ((bb1 & 1u) | ((bb1 & 2u) << 15)) * 0x3F80u;
            }
            #pragma unroll
            for (int j = 0; j < 4; ++j) {     // 64 features = 4 j-tiles
                short8 bf = *reinterpret_cast<const short8*>(&Blds[cur][(j * 16 + fm) * LDB2 + kw * 32 + quad * 8]);
                acc0[j] = __builtin_amdgcn_mfma_f32_16x16x32_bf16(af0.s, bf, acc0[j], 0, 0, 0);
                acc1[j] = __builtin_amdgcn_mfma_f32_16x16x32_bf16(af1.s, bf, acc1[j], 0, 0, 0);
            }
        }
        // T14 stage-split: LDS write LATE into the alternate buffer
        if (ss < 7) {
            #pragma unroll
            for (int i = 0; i < 4; ++i) {
                int idx = i * 256 + t;
                int row = idx >> 4, ch = idx & 15;
                *reinterpret_cast<uint4*>(&Blds[cur ^ 1][row * LDB2 + ch * 8]) = sv[i];
            }
        }
        // single barrier per sub-slice: makes next buffer visible AND separates
        // this iter's reads of Blds[cur] from its overwrite at iter ss+2
        __syncthreads();
    }

    // epilogue: C/D layout col=lane&15, row=quad*4+reg; fp16 private partial per K-split
    unsigned short* out = Cp16 + (size_t)ks * (NAG * NC);
    #pragma unroll
    for (int j = 0; j < 4; ++j) {
        int col = n0 + j * 16 + fm;
        #pragma unroll
        for (int r = 0; r < 4; ++r) {
            int row = row0 + wave * 32 + quad * 4 + r;
            out[(size_t)row * NC + col]        = f2h(acc0[j][r]);
            out[(size_t)(row + 16) * NC + col] = f2h(acc1[j][r]);
        }
    }
}

// ---------------- Kernel 3: deg = popcount(bits row); reduce partials; actor MLP ----------------
__global__ __launch_bounds__(256) void k3_actor(
    const float* __restrict__ h_f32,            // [8192][128]
    const unsigned short* __restrict__ Cp16,    // [NSPLIT][8192][128] fp16
    const unsigned long long* __restrict__ bits,// [8192][128] u64
    const void* __restrict__ W1,                // for dtype self-detection
    const void* __restrict__ W2,                // [256][128]
    const void* __restrict__ b2,                // [128]
    const void* __restrict__ W3,                // [128][16]
    const void* __restrict__ b3,                // [16]
    void* __restrict__ out)                     // [8192][16]
{
    __shared__ float4 comb4[8][66];   // [agent][c-quad], c = 0..255
    __shared__ float hid[8][132];
    __shared__ int degp[8][33];
    __shared__ float inv_lds[8];
    const int t = threadIdx.x;
    const int abase = blockIdx.x * 8;
    const bool isf = detect_f32(W1, t);
    const size_t PS = (size_t)NAG * NC;

    {   // deg: 32 threads per agent, 4 u64 popcounts each (exact integer degree)
        int a = t >> 5, j = t & 31;
        const unsigned long long* bp = bits + (size_t)(abase + a) * 128 + j * 4;
        degp[a][j] = __popcll(bp[0]) + __popcll(bp[1]) + __popcll(bp[2]) + __popcll(bp[3]);
    }
    __syncthreads();
    if (t < 8) {
        int d = 0;
        #pragma unroll
        for (int j = 0; j < 32; ++j) d += degp[t][j];
        inv_lds[t] = 1.0f / fmaxf((float)d, 1.0f);
    }
    __syncthreads();

    // stage comb: 8 agents x 64 c-quads = 512 tasks over 256 threads
    #pragma unroll
    for (int jj = 0; jj < 2; ++jj) {
        int idx = jj * 256 + t;
        int a = idx >> 6, q = idx & 63;
        float4 v;
        if (q < 32) {   // h part
            v = *reinterpret_cast<const float4*>(h_f32 + (size_t)(abase + a) * 128 + q * 4);
        } else {        // msg part: sum NSPLIT fp16 partials, scale by 1/deg
            int f = (q - 32) * 4;
            float s0 = 0.f, s1 = 0.f, s2 = 0.f, s3 = 0.f;
            #pragma unroll
            for (int s = 0; s < NSPLIT; ++s) {
                ushort4 p = *reinterpret_cast<const ushort4*>(Cp16 + s * PS + (size_t)(abase + a) * NC + f);
                s0 += h2f(p.x); s1 += h2f(p.y); s2 += h2f(p.z); s3 += h2f(p.w);
            }
            float sc = inv_lds[a];
            v = make_float4(s0 * sc, s1 * sc, s2 * sc, s3 * sc);
        }
        comb4[a][q] = v;
    }
    __syncthreads();

    const int o = t & 127, half = t >> 7;   // 4 agents per half
    float acc[4];
    if (isf) {
        const float* Wp = (const float*)W2;
        float bias = ((const float*)b2)[o];
        #pragma unroll
        for (int i = 0; i < 4; ++i) acc[i] = bias;
        for (int cq = 0; cq < 64; ++cq) {
            float w0 = Wp[(cq * 4 + 0) * 128 + o];
            float w1 = Wp[(cq * 4 + 1) * 128 + o];
            float w2 = Wp[(cq * 4 + 2) * 128 + o];
            float w3 = Wp[(cq * 4 + 3) * 128 + o];
            #pragma unroll
            for (int i = 0; i < 4; ++i) {
                float4 v = comb4[half * 4 + i][cq];
                acc[i] = fmaf(v.x, w0, acc[i]);
                acc[i] = fmaf(v.y, w1, acc[i]);
                acc[i] = fmaf(v.z, w2, acc[i]);
                acc[i] = fmaf(v.w, w3, acc[i]);
            }
        }
    } else {
        const unsigned short* Wp = (const unsigned short*)W2;
        float bias = bf2f(((const unsigned short*)b2)[o]);
        #pragma unroll
        for (int i = 0; i < 4; ++i) acc[i] = bias;
        for (int cq = 0; cq < 64; ++cq) {
            float w0 = bf2f(Wp[(cq * 4 + 0) * 128 + o]);
            float w1 = bf2f(Wp[(cq * 4 + 1) * 128 + o]);
            float w2 = bf2f(Wp[(cq * 4 + 2) * 128 + o]);
            float w3 = bf2f(Wp[(cq * 4 + 3) * 128 + o]);
            #pragma unroll
            for (int i = 0; i < 4; ++i) {
                float4 v = comb4[half * 4 + i][cq];
                acc[i] = fmaf(v.x, w0, acc[i]);
                acc[i] = fmaf(v.y, w1, acc[i]);
                acc[i] = fmaf(v.z, w2, acc[i]);
                acc[i] = fmaf(v.w, w3, acc[i]);
            }
        }
    }
    #pragma unroll
    for (int i = 0; i < 4; ++i)
        hid[half * 4 + i][o] = tanhf(acc[i]);
    __syncthreads();

    if (t < 128) {   // 8 agents x 16 outputs
        const int q = t & 15, ar = t >> 4;
        float l;
        if (isf) {
            const float* Wp = (const float*)W3;
            l = ((const float*)b3)[q];
            #pragma unroll 4
            for (int oo = 0; oo < 128; ++oo)
                l = fmaf(hid[ar][oo], Wp[oo * 16 + q], l);
        } else {
            const unsigned short* Wp = (const unsigned short*)W3;
            l = bf2f(((const unsigned short*)b3)[q]);
            #pragma unroll 4
            for (int oo = 0; oo < 128; ++oo)
                l = fmaf(hid[ar][oo], bf2f(Wp[oo * 16 + q]), l);
        }
        size_t i0 = (size_t)(abase + ar) * 16 + q;
        if (isf) ((float*)out)[i0] = l;
        else     ((unsigned short*)out)[i0] = f2bf(l);
    }
}

extern "C" void kernel_launch(void* const* d_in, const int* in_sizes, int n_in,
                              void* d_out, int out_size, void* d_ws, size_t ws_size,
                              hipStream_t stream) {
    const void* obs = d_in[0];
    const int*  adj = (const int*)d_in[1];
    const void* W1  = d_in[2];
    const void* b1  = d_in[3];
    const void* W2  = d_in[4];
    const void* b2  = d_in[5];
    const void* W3  = d_in[6];
    const void* b3  = d_in[7];

    char* ws = (char*)d_ws;
    unsigned short* hT   = (unsigned short*)(ws);                    // 128*8192*2   =  2,097,152 B
    float*          h_f32= (float*)(ws + 2097152);                   // 8192*128*4   =  4,194,304 B
    unsigned short* Cp16 = (unsigned short*)(ws + 6291456);          // 8*8192*128*2 = 16,777,216 B
    unsigned long long* bits = (unsigned long long*)(ws + 23068672); // 8192*8192/8  =  8,388,608 B
                                                                     // total ~31.5 MB

    hipLaunchKernelGGL(kA_pack_encode, dim3(2304), dim3(256), 0, stream,
                       adj, bits, obs, W1, b1, h_f32, hT);
    hipLaunchKernelGGL(k2_msggemm, dim3(1024), dim3(256), 0, stream,
                       (const uint32_t*)bits, hT, Cp16);
    hipLaunchKernelGGL(k3_actor, dim3(1024), dim3(256), 0, stream,
                       h_f32, Cp16, bits, W1, W2, b2, W3, b3, d_out);
}

// Round 8
// 434.433 us; speedup vs baseline: 1.0381x; 1.0354x over previous
//
#include <hip/hip_runtime.h>
#include <stdint.h>
#include <math.h>

#define NAG 8192
#define NC  128          // Cp16 row stride: exactly the 128 msg features
#define NSPLIT 8         // K splits of 1024 (fp16 private partials, no atomics)
#define LDB3 68          // B LDS row stride in shorts (64 + 4 pad) -> ~2-way banks, free

typedef __attribute__((ext_vector_type(8))) short short8;
typedef __attribute__((ext_vector_type(4))) float floatx4;

__device__ __forceinline__ float bf2f(unsigned short u) {
    union { uint32_t i; float f; } v; v.i = ((uint32_t)u) << 16; return v.f;
}
__device__ __forceinline__ unsigned short f2bf(float f) {
    union { float f; uint32_t i; } v; v.f = f;
    uint32_t x = v.i;
    return (unsigned short)((x + 0x7FFFu + ((x >> 16) & 1u)) >> 16);  // RNE
}
__device__ __forceinline__ unsigned short f2h(float f) {
    union { _Float16 h; unsigned short u; } v; v.h = (_Float16)f; return v.u;
}
__device__ __forceinline__ float h2f(unsigned short u) {
    union { _Float16 h; unsigned short u; } v; v.u = u; return (float)v.h;
}
// per-wave dtype self-detection (uniform ballot in every wave; no cross-block flag)
__device__ __forceinline__ bool detect_f32(const void* W1, int t) {
    const unsigned short* w = (const unsigned short*)W1;
    int l = t & 63, big = 0;
    #pragma unroll
    for (int j = 0; j < 8; ++j) {
        float v = bf2f(w[l * 8 + j]);
        if (!(fabsf(v) <= 1e6f)) big = 1;   // catches huge and NaN (fp32 mantissa noise)
    }
    return __ballot(big) != 0ull;
}

// ---------------- Kernel A: fused bitpack (blocks 0..2047) + encoder (2048..2303) ----------------
__global__ __launch_bounds__(256) void kA_pack_encode(
    const int* __restrict__ adj,              // [8192][8192] int32 {0,1}
    unsigned long long* __restrict__ bits,    // [8192*8192/64] packed, row-major
    const void* __restrict__ obs,             // [8192][64]
    const void* __restrict__ W1,              // [64][128]
    const void* __restrict__ b1,              // [128]
    float* __restrict__ h_f32,                // [8192][128]
    unsigned short* __restrict__ hT)          // [128][8192] bf16 (features only)
{
    const int t = threadIdx.x;
    if (blockIdx.x < 2048) {
        // ---- bitpack: pure streaming, 1KB contiguous per ballot, 4KB per wave-iter ----
        const int lane = t & 63;
        const int gw = blockIdx.x * 4 + (t >> 6);         // global wave id 0..8191
        for (int it = 0; it < 32; ++it) {
            size_t u = ((size_t)it * 8192 + gw) * 4;      // 4 u64-units per wave per iter
            size_t col = u * 64 + lane;
            unsigned long long m0 = __ballot(adj[col]       != 0);
            unsigned long long m1 = __ballot(adj[col + 64]  != 0);
            unsigned long long m2 = __ballot(adj[col + 128] != 0);
            unsigned long long m3 = __ballot(adj[col + 192] != 0);
            if (lane == 0) {
                bits[u]     = m0;
                bits[u + 1] = m1;
                bits[u + 2] = m2;
                bits[u + 3] = m3;
            }
        }
        return;
    }
    // ---- encoder: h = tanh(obs@W1+b1) ----
    __shared__ float obs_lds[32][68];
    __shared__ unsigned short ht_lds[128][33];
    const int abase = (blockIdx.x - 2048) * 32;
    const bool isf = detect_f32(W1, t);

    {   // stage obs tile 32x64
        int a = t >> 3, c0 = (t & 7) * 8;
        if (isf) {
            const float* p = (const float*)obs;
            #pragma unroll
            for (int j = 0; j < 8; ++j)
                obs_lds[a][c0 + j] = p[(size_t)(abase + a) * 64 + c0 + j];
        } else {
            const unsigned short* p = (const unsigned short*)obs;
            #pragma unroll
            for (int j = 0; j < 8; ++j)
                obs_lds[a][c0 + j] = bf2f(p[(size_t)(abase + a) * 64 + c0 + j]);
        }
    }
    __syncthreads();

    const int o = t & 127;
    const int half = t >> 7;          // wave-uniform
    float acc[16];
    if (isf) {
        const float* Wp = (const float*)W1;
        float bias = ((const float*)b1)[o];
        #pragma unroll
        for (int i = 0; i < 16; ++i) acc[i] = bias;
        for (int k0 = 0; k0 < 64; k0 += 8) {
            float w[8];
            #pragma unroll
            for (int j = 0; j < 8; ++j) w[j] = Wp[(k0 + j) * 128 + o];
            #pragma unroll
            for (int j = 0; j < 8; ++j)
                #pragma unroll
                for (int i = 0; i < 16; ++i)
                    acc[i] = fmaf(obs_lds[half * 16 + i][k0 + j], w[j], acc[i]);
        }
    } else {
        const unsigned short* Wp = (const unsigned short*)W1;
        float bias = bf2f(((const unsigned short*)b1)[o]);
        #pragma unroll
        for (int i = 0; i < 16; ++i) acc[i] = bias;
        for (int k0 = 0; k0 < 64; k0 += 8) {
            float w[8];
            #pragma unroll
            for (int j = 0; j < 8; ++j) w[j] = bf2f(Wp[(k0 + j) * 128 + o]);
            #pragma unroll
            for (int j = 0; j < 8; ++j)
                #pragma unroll
                for (int i = 0; i < 16; ++i)
                    acc[i] = fmaf(obs_lds[half * 16 + i][k0 + j], w[j], acc[i]);
        }
    }
    #pragma unroll
    for (int i = 0; i < 16; ++i) {
        float th = tanhf(acc[i]);
        int a = half * 16 + i;
        h_f32[(size_t)(abase + a) * 128 + o] = th;
        ht_lds[o][a] = f2bf(th);
    }
    __syncthreads();

    for (int p = 0; p < 16; ++p) {    // 128 feature rows only (no constant rows)
        int n = p * 8 + (t >> 5);
        int a = t & 31;
        hT[(size_t)n * NAG + abase + a] = ht_lds[n][a];
    }
}

// ---------------- Kernel 2: Cp16[ks] = bits-adj @ h  (bf16 MFMA, pipelined dbuf) ----------------
// R8: ONE change vs the proven 432-us baseline. Same 64-row M-tile, BN=128, NSPLIT=8,
// grid 1024, LDS 34.8 KB (now 2 x [128][68] bufs), 4 blocks/CU. BK_ss 128->64 with
// double-buffering + T14 split-staging in CORRECT vmcnt order: bits load issued FIRST
// (oldest), stage loads second -> consuming bits waits a COUNTED vmcnt (stage loads
// stay in flight under the 16 MFMAs); ds_write drains them only after the MFMA phase.
// One barrier per sub-slice; intra-block stage/compute overlap that baseline lacked.
__global__ __launch_bounds__(256, 4) void k2_msggemm(
    const uint32_t* __restrict__ bits,        // [8192][256] u32, bit b of word w = col w*32+b
    const unsigned short* __restrict__ hT,    // [128][8192] bf16
    unsigned short* __restrict__ Cp16)        // [NSPLIT][8192][128] fp16
{
    __shared__ __align__(16) unsigned short Blds[2][128 * LDB3];  // 2 x 17,408 B = 34,816 B
    const int t = threadIdx.x;
    const int mtile = blockIdx.x & 127;       // 128 M-tiles of 64 rows
    const int ks = blockIdx.x >> 7;           // 8 K-splits of 1024
    const int row0 = mtile * 64;
    const int kbeg = ks * 1024;

    const int wave = t >> 6, lane = t & 63;
    const int fm = lane & 15, quad = lane >> 4;

    floatx4 acc[8];
    #pragma unroll
    for (int i = 0; i < 8; ++i) acc[i] = (floatx4)0.f;

    const int arow = row0 + wave * 16 + fm;
    const uint32_t* aWp = bits + (size_t)arow * 256 + (kbeg >> 5);

    // staging task decode: 128 rows x 8 chunks(16B) = 1024 tasks over 256 threads = 4 each
    const int srow = t >> 1;                  // rows srow, srow is idx>>3 pattern below
    {   // prologue: stage sub-slice 0 into buffer 0
        #pragma unroll
        for (int i = 0; i < 4; ++i) {
            int idx = i * 256 + t;
            int row = idx >> 3, ch = idx & 7;
            uint4 v = *reinterpret_cast<const uint4*>(hT + (size_t)row * NAG + kbeg + ch * 8);
            *reinterpret_cast<uint4*>(&Blds[0][row * LDB3 + ch * 8]) = v;
        }
        __syncthreads();
    }
    (void)srow;

    #pragma unroll 1
    for (int ss = 0; ss < 16; ++ss) {         // 16 sub-slices of 64 k
        const int cur = ss & 1;
        // (1) bits for this sub-slice: 2 u32 = 64 k. Issued FIRST (oldest in vmcnt FIFO).
        uint2 aw2 = *reinterpret_cast<const uint2*>(aWp + ss * 2);
        // (2) T14 stage-split: next sub-slice's global loads into regs (newer; their
        //     completion is NOT required by the MFMA phase below).
        uint4 sv0, sv1, sv2, sv3;
        if (ss < 15) {
            const unsigned short* src = hT + (size_t)kbeg + (ss + 1) * 64;
            int idx0 = t,       r0 = idx0 >> 3, c0 = idx0 & 7;
            int idx1 = 256 + t, r1 = idx1 >> 3, c1 = idx1 & 7;
            int idx2 = 512 + t, r2 = idx2 >> 3, c2 = idx2 & 7;
            int idx3 = 768 + t, r3 = idx3 >> 3, c3 = idx3 & 7;
            sv0 = *reinterpret_cast<const uint4*>(src + (size_t)r0 * NAG + c0 * 8);
            sv1 = *reinterpret_cast<const uint4*>(src + (size_t)r1 * NAG + c1 * 8);
            sv2 = *reinterpret_cast<const uint4*>(src + (size_t)r2 * NAG + c2 * 8);
            sv3 = *reinterpret_cast<const uint4*>(src + (size_t)r3 * NAG + c3 * 8);
        }
        // (3) MFMA phase on current buffer: waits counted vmcnt for aw2 + lgkm for ds_read;
        //     the 4 stage loads remain in flight underneath.
        #pragma unroll
        for (int kw = 0; kw < 2; ++kw) {      // 2 windows of 32 k
            uint32_t b = ((kw ? aw2.y : aw2.x) >> (quad * 8)) & 0xFFu;
            union { uint32_t u[4]; short8 s; } af;
            #pragma unroll
            for (int p = 0; p < 4; ++p) {
                uint32_t bb = b >> (2 * p);
                af.u[p] = ((bb & 1u) | ((bb & 2u) << 15)) * 0x3F80u;   // {0,1}->bf16 pair, exact
            }
            #pragma unroll
            for (int j = 0; j < 8; ++j) {
                short8 bf = *reinterpret_cast<const short8*>(&Blds[cur][(j * 16 + fm) * LDB3 + kw * 32 + quad * 8]);
                acc[j] = __builtin_amdgcn_mfma_f32_16x16x32_bf16(af.s, bf, acc[j], 0, 0, 0);
            }
        }
        // (4) write staged regs into the alternate buffer (drains vmcnt AFTER the MFMAs).
        //     Safe: buffer cur^1 was last read in iter ss-1, sealed by that iter's barrier.
        if (ss < 15) {
            *reinterpret_cast<uint4*>(&Blds[cur ^ 1][((t      ) >> 3) * LDB3 + (t & 7) * 8])        = sv0;
            *reinterpret_cast<uint4*>(&Blds[cur ^ 1][((256 + t) >> 3) * LDB3 + ((256 + t) & 7) * 8]) = sv1;
            *reinterpret_cast<uint4*>(&Blds[cur ^ 1][((512 + t) >> 3) * LDB3 + ((512 + t) & 7) * 8]) = sv2;
            *reinterpret_cast<uint4*>(&Blds[cur ^ 1][((768 + t) >> 3) * LDB3 + ((768 + t) & 7) * 8]) = sv3;
        }
        // (5) single barrier per sub-slice: publishes next buffer, seals current reads.
        __syncthreads();
    }

    // epilogue: C/D layout col=lane&15, row=quad*4+reg; fp16 private partial per K-split
    unsigned short* out = Cp16 + (size_t)ks * (NAG * NC);
    #pragma unroll
    for (int j = 0; j < 8; ++j) {
        int col = j * 16 + fm;
        #pragma unroll
        for (int r = 0; r < 4; ++r) {
            int row = row0 + wave * 16 + quad * 4 + r;
            out[(size_t)row * NC + col] = f2h(acc[j][r]);
        }
    }
}

// ---------------- Kernel 3: deg = popcount(bits row); reduce partials; actor MLP ----------------
__global__ __launch_bounds__(256) void k3_actor(
    const float* __restrict__ h_f32,            // [8192][128]
    const unsigned short* __restrict__ Cp16,    // [NSPLIT][8192][128] fp16
    const unsigned long long* __restrict__ bits,// [8192][128] u64
    const void* __restrict__ W1,                // for dtype self-detection
    const void* __restrict__ W2,                // [256][128]
    const void* __restrict__ b2,                // [128]
    const void* __restrict__ W3,                // [128][16]
    const void* __restrict__ b3,                // [16]
    void* __restrict__ out)                     // [8192][16]
{
    __shared__ float4 comb4[8][66];   // [agent][c-quad], c = 0..255
    __shared__ float hid[8][132];
    __shared__ int degp[8][33];
    __shared__ float inv_lds[8];
    const int t = threadIdx.x;
    const int abase = blockIdx.x * 8;
    const bool isf = detect_f32(W1, t);
    const size_t PS = (size_t)NAG * NC;

    {   // deg: 32 threads per agent, 4 u64 popcounts each (exact integer degree)
        int a = t >> 5, j = t & 31;
        const unsigned long long* bp = bits + (size_t)(abase + a) * 128 + j * 4;
        degp[a][j] = __popcll(bp[0]) + __popcll(bp[1]) + __popcll(bp[2]) + __popcll(bp[3]);
    }
    __syncthreads();
    if (t < 8) {
        int d = 0;
        #pragma unroll
        for (int j = 0; j < 32; ++j) d += degp[t][j];
        inv_lds[t] = 1.0f / fmaxf((float)d, 1.0f);
    }
    __syncthreads();

    // stage comb: 8 agents x 64 c-quads = 512 tasks over 256 threads
    #pragma unroll
    for (int jj = 0; jj < 2; ++jj) {
        int idx = jj * 256 + t;
        int a = idx >> 6, q = idx & 63;
        float4 v;
        if (q < 32) {   // h part
            v = *reinterpret_cast<const float4*>(h_f32 + (size_t)(abase + a) * 128 + q * 4);
        } else {        // msg part: sum NSPLIT fp16 partials, scale by 1/deg
            int f = (q - 32) * 4;
            float s0 = 0.f, s1 = 0.f, s2 = 0.f, s3 = 0.f;
            #pragma unroll
            for (int s = 0; s < NSPLIT; ++s) {
                ushort4 p = *reinterpret_cast<const ushort4*>(Cp16 + s * PS + (size_t)(abase + a) * NC + f);
                s0 += h2f(p.x); s1 += h2f(p.y); s2 += h2f(p.z); s3 += h2f(p.w);
            }
            float sc = inv_lds[a];
            v = make_float4(s0 * sc, s1 * sc, s2 * sc, s3 * sc);
        }
        comb4[a][q] = v;
    }
    __syncthreads();

    const int o = t & 127, half = t >> 7;   // 4 agents per half
    float acc[4];
    if (isf) {
        const float* Wp = (const float*)W2;
        float bias = ((const float*)b2)[o];
        #pragma unroll
        for (int i = 0; i < 4; ++i) acc[i] = bias;
        for (int cq = 0; cq < 64; ++cq) {
            float w0 = Wp[(cq * 4 + 0) * 128 + o];
            float w1 = Wp[(cq * 4 + 1) * 128 + o];
            float w2 = Wp[(cq * 4 + 2) * 128 + o];
            float w3 = Wp[(cq * 4 + 3) * 128 + o];
            #pragma unroll
            for (int i = 0; i < 4; ++i) {
                float4 v = comb4[half * 4 + i][cq];
                acc[i] = fmaf(v.x, w0, acc[i]);
                acc[i] = fmaf(v.y, w1, acc[i]);
                acc[i] = fmaf(v.z, w2, acc[i]);
                acc[i] = fmaf(v.w, w3, acc[i]);
            }
        }
    } else {
        const unsigned short* Wp = (const unsigned short*)W2;
        float bias = bf2f(((const unsigned short*)b2)[o]);
        #pragma unroll
        for (int i = 0; i < 4; ++i) acc[i] = bias;
        for (int cq = 0; cq < 64; ++cq) {
            float w0 = bf2f(Wp[(cq * 4 + 0) * 128 + o]);
            float w1 = bf2f(Wp[(cq * 4 + 1) * 128 + o]);
            float w2 = bf2f(Wp[(cq * 4 + 2) * 128 + o]);
            float w3 = bf2f(Wp[(cq * 4 + 3) * 128 + o]);
            #pragma unroll
            for (int i = 0; i < 4; ++i) {
                float4 v = comb4[half * 4 + i][cq];
                acc[i] = fmaf(v.x, w0, acc[i]);
                acc[i] = fmaf(v.y, w1, acc[i]);
                acc[i] = fmaf(v.z, w2, acc[i]);
                acc[i] = fmaf(v.w, w3, acc[i]);
            }
        }
    }
    #pragma unroll
    for (int i = 0; i < 4; ++i)
        hid[half * 4 + i][o] = tanhf(acc[i]);
    __syncthreads();

    if (t < 128) {   // 8 agents x 16 outputs
        const int q = t & 15, ar = t >> 4;
        float l;
        if (isf) {
            const float* Wp = (const float*)W3;
            l = ((const float*)b3)[q];
            #pragma unroll 4
            for (int oo = 0; oo < 128; ++oo)
                l = fmaf(hid[ar][oo], Wp[oo * 16 + q], l);
        } else {
            const unsigned short* Wp = (const unsigned short*)W3;
            l = bf2f(((const unsigned short*)b3)[q]);
            #pragma unroll 4
            for (int oo = 0; oo < 128; ++oo)
                l = fmaf(hid[ar][oo], bf2f(Wp[oo * 16 + q]), l);
        }
        size_t i0 = (size_t)(abase + ar) * 16 + q;
        if (isf) ((float*)out)[i0] = l;
        else     ((unsigned short*)out)[i0] = f2bf(l);
    }
}

extern "C" void kernel_launch(void* const* d_in, const int* in_sizes, int n_in,
                              void* d_out, int out_size, void* d_ws, size_t ws_size,
                              hipStream_t stream) {
    const void* obs = d_in[0];
    const int*  adj = (const int*)d_in[1];
    const void* W1  = d_in[2];
    const void* b1  = d_in[3];
    const void* W2  = d_in[4];
    const void* b2  = d_in[5];
    const void* W3  = d_in[6];
    const void* b3  = d_in[7];

    char* ws = (char*)d_ws;
    unsigned short* hT   = (unsigned short*)(ws);                    // 128*8192*2   =  2,097,152 B
    float*          h_f32= (float*)(ws + 2097152);                   // 8192*128*4   =  4,194,304 B
    unsigned short* Cp16 = (unsigned short*)(ws + 6291456);          // 8*8192*128*2 = 16,777,216 B
    unsigned long long* bits = (unsigned long long*)(ws + 23068672); // 8192*8192/8  =  8,388,608 B
                                                                     // total ~31.5 MB

    hipLaunchKernelGGL(kA_pack_encode, dim3(2304), dim3(256), 0, stream,
                       adj, bits, obs, W1, b1, h_f32, hT);
    hipLaunchKernelGGL(k2_msggemm, dim3(1024), dim3(256), 0, stream,
                       (const uint32_t*)bits, hT, Cp16);
    hipLaunchKernelGGL(k3_actor, dim3(1024), dim3(256), 0, stream,
                       h_f32, Cp16, bits, W1, W2, b2, W3, b3, d_out);
}